// Round 4
// baseline (9390.438 us; speedup 1.0000x reference)
//
#include <hip/hip_runtime.h>

typedef unsigned short u16;
typedef unsigned int u32;
typedef unsigned long long u64;
typedef __bf16 bf16x8 __attribute__((ext_vector_type(8)));
typedef float f32x4 __attribute__((ext_vector_type(4)));

#define T_LEN 512
#define BATCH 64
#define FIN 128
#define UNITS 1024
#define H_STRIDE 65536              // elements per parity buffer (64 rows * 1024)

// ---- workspace layout (bytes) ----
#define O_BAR   0
#define SZ_BAR  8192
#define O_XBF   SZ_BAR
#define SZ_XBF  (T_LEN*BATCH*FIN*2)
#define O_WP0   (O_XBF + SZ_XBF)
#define SZ_WP0  (1152*4096*2)
#define O_WP1   (O_WP0 + SZ_WP0)
#define SZ_WP1  (2048*4096*2)
#define O_WFC   (O_WP1 + SZ_WP1)
#define SZ_WFC  (16*1024*2)
#define O_H0    (O_WFC + SZ_WFC)
#define SZ_H    (2*H_STRIDE*2)      // 2 parities
#define O_H1    (O_H0 + SZ_H)
#define WS_NEED (O_H1 + SZ_H)

__device__ __forceinline__ float bf2f(u16 s) {
  u32 u = ((u32)s) << 16;
  return __builtin_bit_cast(float, u);
}
__device__ __forceinline__ u16 f2bf(float f) {
  u32 u = __builtin_bit_cast(u32, f);
  u32 r = (u + 0x7FFFu + ((u >> 16) & 1u)) >> 16;
  return (u16)r;
}
__device__ __forceinline__ float sigm(float x) { return 1.0f / (1.0f + __expf(-x)); }
__device__ __forceinline__ float tanhft(float x) { return 1.0f - 2.0f / (__expf(2.0f * x) + 1.0f); }

// coherent (LLC, bypass stale L1/L2) 16B load as 2x relaxed agent u64 atomics — no buffer_inv
__device__ __forceinline__ uint4 ldh16(const u16* q) {
  u64 a = __hip_atomic_load((const u64*)q,     __ATOMIC_RELAXED, __HIP_MEMORY_SCOPE_AGENT);
  u64 b = __hip_atomic_load((const u64*)q + 1, __ATOMIC_RELAXED, __HIP_MEMORY_SCOPE_AGENT);
  uint4 r; r.x = (u32)a; r.y = (u32)(a >> 32); r.z = (u32)b; r.w = (u32)(b >> 32);
  return r;
}
__device__ __forceinline__ void sth(u16* q, u16 v) {
  __hip_atomic_store(q, v, __ATOMIC_RELAXED, __HIP_MEMORY_SCOPE_AGENT);
}

// ---------------- prep kernels ----------------
__global__ void k_zero(u32* p, int n) {
  int i = blockIdx.x * 256 + threadIdx.x;
  if (i < n) p[i] = 0u;
}

__global__ void k_pack_x(const float* __restrict__ src, u16* __restrict__ dst) {
  int i = blockIdx.x * 256 + threadIdx.x;      // < 512*64*128
  int f = i & 127, tb = i >> 7;
  int b = tb & 63, t = tb >> 6;
  dst[i] = f2bf(src[(b * T_LEN + t) * FIN + f]);
}

// Wp0: [ug][nt][ktg(36)][lane][8] over K=[W0(128);U0(1024)], cols unit-gate interleaved
__global__ void k_pack_w0(const float* __restrict__ W0, const float* __restrict__ U0,
                          u16* __restrict__ dst) {
  int i = blockIdx.x * 256 + threadIdx.x;      // < 4096*1152
  int j = i & 7, lane = (i >> 3) & 63, rest = i >> 9;
  int ktg = rest % 36, tmp = rest / 36;
  int nt = tmp & 3, ug = tmp >> 2;
  int k = ktg * 32 + ((lane >> 4) << 3) + j;
  int rr = nt * 16 + (lane & 15);
  int gate = rr & 3, ul = rr >> 2;
  int col = gate * 1024 + ug * 16 + ul;
  float v = (k < FIN) ? W0[k * 4096 + col] : U0[(k - FIN) * 4096 + col];
  dst[i] = f2bf(v);
}

// Wp1: [ug][nt][ktg(64)][lane][8] over K=[W1(1024);U1(1024)]
__global__ void k_pack_w1(const float* __restrict__ W1, const float* __restrict__ U1,
                          u16* __restrict__ dst) {
  int i = blockIdx.x * 256 + threadIdx.x;      // < 4096*2048
  int j = i & 7, lane = (i >> 3) & 63, rest = i >> 9;
  int ktg = rest & 63, tmp = rest >> 6;
  int nt = tmp & 3, ug = tmp >> 2;
  int k = ktg * 32 + ((lane >> 4) << 3) + j;
  int rr = nt * 16 + (lane & 15);
  int gate = rr & 3, ul = rr >> 2;
  int col = gate * 1024 + ug * 16 + ul;
  float v = (k < UNITS) ? W1[k * 4096 + col] : U1[(k - UNITS) * 4096 + col];
  dst[i] = f2bf(v);
}

__global__ void k_pack_wfc(const float* __restrict__ Wfc, u16* __restrict__ dst) {
  int i = blockIdx.x * 256 + threadIdx.x;      // < 16*1024
  int k = i & 1023, c = i >> 10;
  dst[c * 1024 + k] = f2bf(Wfc[k * 16 + c]);
}

// ---------------- persistent kernel ----------------
struct KP {
  const u16* xbf; const u16* wp0; const u16* wp1; const u16* wfc;
  u16* h0; u16* h1; u32* bar;
  const float* b0; const float* g0; const float* be0;
  const float* b1; const float* g1; const float* be1;
  const float* bfc; float* out;
};

__device__ __forceinline__ void accst(uint4 v, float& s1, float& s2) {
  u32 a[4] = {v.x, v.y, v.z, v.w};
#pragma unroll
  for (int e = 0; e < 4; ++e) {
    float f0 = bf2f((u16)(a[e] & 0xffffu));
    float f1 = bf2f((u16)(a[e] >> 16));
    s1 += f0 + f1;
    s2 += f0 * f0 + f1 * f1;
  }
}

__device__ __forceinline__ uint4 normpack(uint4 v, float mu, float rs,
                                          const float* gg, const float* bb) {
  u32 a[4] = {v.x, v.y, v.z, v.w};
  u32 o[4];
#pragma unroll
  for (int e = 0; e < 4; ++e) {
    float f0 = (bf2f((u16)(a[e] & 0xffffu)) - mu) * rs * gg[2 * e] + bb[2 * e];
    float f1 = (bf2f((u16)(a[e] >> 16)) - mu) * rs * gg[2 * e + 1] + bb[2 * e + 1];
    o[e] = (u32)f2bf(f0) | ((u32)f2bf(f1) << 16);
  }
  uint4 r; r.x = o[0]; r.y = o[1]; r.z = o[2]; r.w = o[3];
  return r;
}

// all-to-all flag barrier over the 64 blocks of one batch-group.
// RELAXED agent-scope only (no buffer_inv/buffer_wbl2 — the R2 killer).
// Single LLC hop: each block stores its flag; wave 0's 64 lanes poll all 64
// flags and ballot (removes R3's leader->gen second round trip).
// __syncthreads() on entry drains vmcnt(0) => prior coherent stores visible.
__device__ __forceinline__ void barrier_bg(u32* flags, int ug, int lane, int wv, u32 ep) {
  __syncthreads();
  if (wv == 0) {
    if (lane == 0)
      __hip_atomic_store(flags + ug * 4, ep, __ATOMIC_RELAXED, __HIP_MEMORY_SCOPE_AGENT);
    for (;;) {
      u32 v = __hip_atomic_load(flags + lane * 4, __ATOMIC_RELAXED, __HIP_MEMORY_SCOPE_AGENT);
      if (__ballot(v >= ep) == ~0ull) break;
      __builtin_amdgcn_s_sleep(1);
    }
  }
  __syncthreads();
  asm volatile("" ::: "memory");
}

// FC + softmax for one output row (row = bg*16+ug), using bufB (raw h1) and
// mu_s/sg_s (its LN stats). Block-uniform entry; contains __syncthreads.
__device__ __forceinline__ void fc_out(int tid, int ug, int bg, int t,
    u16 (*bufB)[1032], u16 (*buf0)[1032], float (*zb0)[68],
    const float* mu_s, const float* sg_s, float* lbuf,
    float g1a, float g1b, float be1a, float be1b,
    const u16* __restrict__ wfc, const float* __restrict__ bfc,
    float* __restrict__ out) {
  const int row = bg * 16 + ug;
  u32 hv = *(const u32*)&bufB[ug][tid * 2];
  float f0 = bf2f((u16)(hv & 0xffffu)), f1 = bf2f((u16)(hv >> 16));
  {
    float mu = mu_s[ug], rs = sg_s[ug];
    float* o1f = (float*)&buf0[0][0];
    o1f[tid * 2]     = (f0 - mu) * rs * g1a + be1a;
    o1f[tid * 2 + 1] = (f1 - mu) * rs * g1b + be1b;
  }
  __syncthreads();
  if (tid < 256) {
    const int cls = tid & 15, ks = tid >> 4;
    const float* o1f = (const float*)&buf0[0][0];
    const u16* wrow = wfc + cls * 1024 + ks * 64;
    float pa = 0.f;
#pragma unroll
    for (int q8 = 0; q8 < 8; ++q8) {
      uint4 wv4 = *(const uint4*)(wrow + q8 * 8);
      u32 aa[4] = {wv4.x, wv4.y, wv4.z, wv4.w};
#pragma unroll
      for (int e = 0; e < 4; ++e) {
        int k = ks * 64 + q8 * 8 + e * 2;
        pa += o1f[k]     * bf2f((u16)(aa[e] & 0xffffu));
        pa += o1f[k + 1] * bf2f((u16)(aa[e] >> 16));
      }
    }
    zb0[ks][cls] = pa;
  }
  __syncthreads();
  if (tid < 16) {
    float lg = bfc[tid];
#pragma unroll
    for (int ks = 0; ks < 16; ++ks) lg += zb0[ks][tid];
    lbuf[tid] = lg;
  }
  __syncthreads();
  if (tid < 16) {
    float mx = lbuf[0];
#pragma unroll
    for (int j2 = 1; j2 < 16; ++j2) mx = fmaxf(mx, lbuf[j2]);
    float ssum = 0.f;
#pragma unroll
    for (int j2 = 0; j2 < 16; ++j2) ssum += __expf(lbuf[j2] - mx);
    out[((size_t)row * T_LEN + t) * 16 + tid] = __expf(lbuf[tid] - mx) / ssum;
  }
  __syncthreads();  // protect buf0/zb scratch against next step's writes
}

__global__ void __launch_bounds__(512, 2) k_persist(KP p) {
  const int tid = threadIdx.x;
  const int ug = blockIdx.x & 63, bg = blockIdx.x >> 6;
  const int lane = tid & 63, wv = tid >> 6;
  const int nt = wv & 3, kh = wv >> 2;

  __shared__ __align__(16) u16 bufA[16][1032];  // raw h0(t-1), carried across steps
  __shared__ __align__(16) u16 bufB[16][1032];  // raw h1(t-1) (this step's L1 input + FC)
  __shared__ __align__(16) u16 buf0[16][1032];  // o0(t) staging; FC float scratch (aliased)
  __shared__ float zb[2][16][68];               // kh-partial z tiles
  __shared__ float g0s[1024], be0s[1024];
  __shared__ float b0s[64], b1s[64];
  __shared__ float mu_s[16], sg_s[16];          // LN1 stats of h1(t-1) (for FC)
  __shared__ float lbuf[16];

  for (int i = tid; i < 1024; i += 512) { g0s[i] = p.g0[i]; be0s[i] = p.be0[i]; }
  if (tid < 64) {
    int gate = tid & 3, ul = tid >> 2;
    b0s[tid] = p.b0[gate * 1024 + ug * 16 + ul];
    b1s[tid] = p.b1[gate * 1024 + ug * 16 + ul];
  }
  // zero bufA: L0 at t=0 reads h0(-1)=0 from it
  {
    u32* za = (u32*)&bufA[0][0];
    for (int i = tid; i < 16 * 1032 / 2; i += 512) za[i] = 0u;
  }
  const float g1a = p.g1[tid * 2], g1b = p.g1[tid * 2 + 1];
  const float be1a = p.be1[tid * 2], be1b = p.be1[tid * 2 + 1];

  // resident weight fragments (bf16, MFMA B-operand order); ~200 regs in the
  // unified VGPR/AGPR file — launch_bounds(512,2) keeps the 256-reg budget.
  bf16x8 w0r[18], w1r[32];
  {
    const u16* q0 = p.wp0 + (size_t)(((ug * 4 + nt) * 36 + kh * 18) * 64 + lane) * 8;
#pragma unroll
    for (int s = 0; s < 18; ++s)
      w0r[s] = __builtin_bit_cast(bf16x8, *(const uint4*)(q0 + (size_t)s * 512));
    const u16* q1 = p.wp1 + (size_t)(((ug * 4 + nt) * 64 + kh * 32) * 64 + lane) * 8;
#pragma unroll
    for (int s = 0; s < 32; ++s)
      w1r[s] = __builtin_bit_cast(bf16x8, *(const uint4*)(q1 + (size_t)s * 512));
  }

  u32* flags = p.bar + bg * 256;                // 64 flags * 16B spacing per bg

  float c0 = 0.f, c1 = 0.f;                     // cell state, tid<256: (row=tid>>4, unit=tid&15)
  const int gr = tid >> 4, gu = tid & 15;
  const int srow = tid >> 5, ssub = tid & 31;   // row-staging map (32 thr/row)
  const int am = lane & 15, aq = (lane >> 4) << 3;  // A-frag: row=lane&15, k += (lane>>4)*8

  __syncthreads();

  for (int t = 0; t < T_LEN; ++t) {
    const int cur = t & 1, rd = cur ^ 1;

    // ======== L0 MFMA: z0 = [x(t) | h0(t-1)] @ Wp0 (x global-cached, h0 from bufA) ====
    f32x4 acc0 = {0.f, 0.f, 0.f, 0.f};
    if (kh == 0) {
      const u16* xr = p.xbf + (size_t)(t * 64 + bg * 16 + am) * FIN + aq;
#pragma unroll
      for (int s = 0; s < 4; ++s) {            // k in [0,128): x
        bf16x8 a = __builtin_bit_cast(bf16x8, *(const uint4*)(xr + s * 32));
        acc0 = __builtin_amdgcn_mfma_f32_16x16x32_bf16(a, w0r[s], acc0, 0, 0, 0);
      }
#pragma unroll
      for (int s = 4; s < 18; ++s) {           // k in [128,576): h0[0..448)
        bf16x8 a = __builtin_bit_cast(bf16x8, *(const uint4*)&bufA[am][s * 32 + aq - 128]);
        acc0 = __builtin_amdgcn_mfma_f32_16x16x32_bf16(a, w0r[s], acc0, 0, 0, 0);
      }
    } else {
#pragma unroll
      for (int s = 0; s < 18; ++s) {           // k in [576,1152): h0[448..1024)
        bf16x8 a = __builtin_bit_cast(bf16x8, *(const uint4*)&bufA[am][448 + s * 32 + aq]);
        acc0 = __builtin_amdgcn_mfma_f32_16x16x32_bf16(a, w0r[s], acc0, 0, 0, 0);
      }
    }
#pragma unroll
    for (int i = 0; i < 4; ++i)
      zb[kh][(lane >> 4) * 4 + i][nt * 16 + (lane & 15)] = acc0[i];
    __syncthreads();

    // ======== gates layer0 -> coherent store of h0(t) (parity cur) ========
    if (tid < 256) {
      const float* zr0 = &zb[0][gr][gu * 4];
      const float* zr1 = &zb[1][gr][gu * 4];
      float zi = zr0[0] + zr1[0] + b0s[gu * 4 + 0];
      float zf = zr0[1] + zr1[1] + b0s[gu * 4 + 1];
      float zg = zr0[2] + zr1[2] + b0s[gu * 4 + 2];
      float zo = zr0[3] + zr1[3] + b0s[gu * 4 + 3];
      float gi = sigm(zi), gf = sigm(zf), gg = tanhft(zg), go = sigm(zo);
      c0 = gf * c0 + gi * gg;
      float h = go * tanhft(c0);
      sth(p.h0 + (size_t)cur * H_STRIDE + (size_t)(bg * 16 + gr) * UNITS + ug * 16 + gu,
          f2bf(h));
    }
    // ---- THE barrier: h0(t) visible; also (transitively) h1(t-1) from step t-1 ----
    barrier_bg(flags, ug, lane, wv, (u32)(t + 1));

    // ======== overlapped gather: h0(t) [parity cur] + h1(t-1) [parity rd] ========
    {
      const u16* h0r = p.h0 + (size_t)cur * H_STRIDE + (size_t)(bg * 16 + srow) * UNITS + ssub * 8;
      const u16* h1r = p.h1 + (size_t)rd  * H_STRIDE + (size_t)(bg * 16 + srow) * UNITS + ssub * 8;
      uint4 a0 = ldh16(h0r);
      uint4 a1 = ldh16(h0r + 256);
      uint4 a2 = ldh16(h0r + 512);
      uint4 a3 = ldh16(h0r + 768);
      uint4 b0 = ldh16(h1r);
      uint4 b1 = ldh16(h1r + 256);
      uint4 b2 = ldh16(h1r + 512);
      uint4 b3 = ldh16(h1r + 768);

      // LN0 stats: 32-lane butterfly -> every lane holds mu0/rs0 (no LDS, no sync)
      float s1 = 0.f, s2 = 0.f;
      accst(a0, s1, s2); accst(a1, s1, s2); accst(a2, s1, s2); accst(a3, s1, s2);
#pragma unroll
      for (int m = 1; m <= 16; m <<= 1) { s1 += __shfl_xor(s1, m); s2 += __shfl_xor(s2, m); }
      float mu0 = s1 * (1.0f / 1024.0f);
      float rs0 = rsqrtf(s2 * (1.0f / 1024.0f) - mu0 * mu0 + 1e-3f);

      *(uint4*)&bufA[srow][ssub * 8]       = a0;    // raw h0(t) for next step's L0
      *(uint4*)&bufA[srow][256 + ssub * 8] = a1;
      *(uint4*)&bufA[srow][512 + ssub * 8] = a2;
      *(uint4*)&bufA[srow][768 + ssub * 8] = a3;

      // LN1 stats of h1(t-1) (for deferred FC)
      float u1 = 0.f, u2 = 0.f;
      accst(b0, u1, u2); accst(b1, u1, u2); accst(b2, u1, u2); accst(b3, u1, u2);
#pragma unroll
      for (int m = 1; m <= 16; m <<= 1) { u1 += __shfl_xor(u1, m); u2 += __shfl_xor(u2, m); }
      if (ssub == 0) {
        float mu = u1 * (1.0f / 1024.0f);
        mu_s[srow] = mu;
        sg_s[srow] = rsqrtf(u2 * (1.0f / 1024.0f) - mu * mu + 1e-3f);
      }
      *(uint4*)&bufB[srow][ssub * 8]       = b0;    // raw h1(t-1) for this step's L1 + FC
      *(uint4*)&bufB[srow][256 + ssub * 8] = b1;
      *(uint4*)&bufB[srow][512 + ssub * 8] = b2;
      *(uint4*)&bufB[srow][768 + ssub * 8] = b3;

      // o0(t) = LN(h0(t)) -> buf0
      *(uint4*)&buf0[srow][ssub * 8]       = normpack(a0, mu0, rs0, &g0s[ssub * 8], &be0s[ssub * 8]);
      *(uint4*)&buf0[srow][256 + ssub * 8] = normpack(a1, mu0, rs0, &g0s[256 + ssub * 8], &be0s[256 + ssub * 8]);
      *(uint4*)&buf0[srow][512 + ssub * 8] = normpack(a2, mu0, rs0, &g0s[512 + ssub * 8], &be0s[512 + ssub * 8]);
      *(uint4*)&buf0[srow][768 + ssub * 8] = normpack(a3, mu0, rs0, &g0s[768 + ssub * 8], &be0s[768 + ssub * 8]);
    }
    __syncthreads();

    // ======== L1 MFMA: A = [o0(t) | h1(t-1)], kh0 from buf0, kh1 from bufB ========
    f32x4 acc1 = {0.f, 0.f, 0.f, 0.f};
    if (kh == 0) {
#pragma unroll
      for (int s = 0; s < 32; ++s) {
        bf16x8 a = __builtin_bit_cast(bf16x8, *(const uint4*)&buf0[am][s * 32 + aq]);
        acc1 = __builtin_amdgcn_mfma_f32_16x16x32_bf16(a, w1r[s], acc1, 0, 0, 0);
      }
    } else {
#pragma unroll
      for (int s = 0; s < 32; ++s) {
        bf16x8 a = __builtin_bit_cast(bf16x8, *(const uint4*)&bufB[am][s * 32 + aq]);
        acc1 = __builtin_amdgcn_mfma_f32_16x16x32_bf16(a, w1r[s], acc1, 0, 0, 0);
      }
    }
#pragma unroll
    for (int i = 0; i < 4; ++i)
      zb[kh][(lane >> 4) * 4 + i][nt * 16 + (lane & 15)] = acc1[i];
    __syncthreads();

    // ======== gates layer1 -> coherent store of h1(t) (parity cur) ========
    if (tid < 256) {
      const float* zr0 = &zb[0][gr][gu * 4];
      const float* zr1 = &zb[1][gr][gu * 4];
      float zi = zr0[0] + zr1[0] + b1s[gu * 4 + 0];
      float zf = zr0[1] + zr1[1] + b1s[gu * 4 + 1];
      float zg = zr0[2] + zr1[2] + b1s[gu * 4 + 2];
      float zo = zr0[3] + zr1[3] + b1s[gu * 4 + 3];
      float gi = sigm(zi), gf = sigm(zf), gg = tanhft(zg), go = sigm(zo);
      c1 = gf * c1 + gi * gg;
      float h = go * tanhft(c1);
      sth(p.h1 + (size_t)cur * H_STRIDE + (size_t)(bg * 16 + gr) * UNITS + ug * 16 + gu,
          f2bf(h));
    }

    // ======== deferred FC(t-1) from bufB + mu_s/sg_s (doesn't gate the recurrence) ====
    if (ug < 16 && t > 0)
      fc_out(tid, ug, bg, t - 1, bufB, buf0, zb[0], mu_s, sg_s, lbuf,
             g1a, g1b, be1a, be1b, p.wfc, p.bfc, p.out);
  }

  // ======== epilogue: FC(T-1) needs h1(511) gathered ========
  barrier_bg(flags, ug, lane, wv, (u32)(T_LEN + 1));
  {
    const u16* h1r = p.h1 + (size_t)((T_LEN - 1) & 1) * H_STRIDE
                   + (size_t)(bg * 16 + srow) * UNITS + ssub * 8;
    uint4 b0 = ldh16(h1r);
    uint4 b1 = ldh16(h1r + 256);
    uint4 b2 = ldh16(h1r + 512);
    uint4 b3 = ldh16(h1r + 768);
    float u1 = 0.f, u2 = 0.f;
    accst(b0, u1, u2); accst(b1, u1, u2); accst(b2, u1, u2); accst(b3, u1, u2);
#pragma unroll
    for (int m = 1; m <= 16; m <<= 1) { u1 += __shfl_xor(u1, m); u2 += __shfl_xor(u2, m); }
    if (ssub == 0) {
      float mu = u1 * (1.0f / 1024.0f);
      mu_s[srow] = mu;
      sg_s[srow] = rsqrtf(u2 * (1.0f / 1024.0f) - mu * mu + 1e-3f);
    }
    *(uint4*)&bufB[srow][ssub * 8]       = b0;
    *(uint4*)&bufB[srow][256 + ssub * 8] = b1;
    *(uint4*)&bufB[srow][512 + ssub * 8] = b2;
    *(uint4*)&bufB[srow][768 + ssub * 8] = b3;
  }
  __syncthreads();
  if (ug < 16)
    fc_out(tid, ug, bg, T_LEN - 1, bufB, buf0, zb[0], mu_s, sg_s, lbuf,
           g1a, g1b, be1a, be1b, p.wfc, p.bfc, p.out);
}

extern "C" void kernel_launch(void* const* d_in, const int* in_sizes, int n_in,
                              void* d_out, int out_size, void* d_ws, size_t ws_size,
                              hipStream_t stream) {
  (void)in_sizes; (void)n_in; (void)out_size;
  if (ws_size < (size_t)WS_NEED) return;

  const float* inp = (const float*)d_in[0];
  const float* W0  = (const float*)d_in[1];
  const float* U0  = (const float*)d_in[2];
  const float* b0  = (const float*)d_in[3];
  const float* g0  = (const float*)d_in[4];
  const float* be0 = (const float*)d_in[5];
  const float* W1  = (const float*)d_in[6];
  const float* U1  = (const float*)d_in[7];
  const float* b1  = (const float*)d_in[8];
  const float* g1  = (const float*)d_in[9];
  const float* be1 = (const float*)d_in[10];
  const float* Wfc = (const float*)d_in[11];
  const float* bfc = (const float*)d_in[12];

  char* ws = (char*)d_ws;
  u32* bar  = (u32*)(ws + O_BAR);
  u16* xbf  = (u16*)(ws + O_XBF);
  u16* wp0  = (u16*)(ws + O_WP0);
  u16* wp1  = (u16*)(ws + O_WP1);
  u16* wfcT = (u16*)(ws + O_WFC);
  u16* h0   = (u16*)(ws + O_H0);
  u16* h1   = (u16*)(ws + O_H1);

  k_zero<<<8, 256, 0, stream>>>(bar, 2048);
  k_zero<<<512, 256, 0, stream>>>((u32*)(ws + O_H0), (SZ_H + SZ_H) / 4);  // h0+h1 both parities
  k_pack_x<<<16384, 256, 0, stream>>>(inp, xbf);
  k_pack_w0<<<18432, 256, 0, stream>>>(W0, U0, wp0);
  k_pack_w1<<<32768, 256, 0, stream>>>(W1, U1, wp1);
  k_pack_wfc<<<64, 256, 0, stream>>>(Wfc, wfcT);

  KP p;
  p.xbf = xbf; p.wp0 = wp0; p.wp1 = wp1; p.wfc = wfcT;
  p.h0 = h0; p.h1 = h1; p.bar = bar;
  p.b0 = b0; p.g0 = g0; p.be0 = be0;
  p.b1 = b1; p.g1 = g1; p.be1 = be1;
  p.bfc = bfc; p.out = (float*)d_out;

  void* args[] = { &p };
  hipLaunchCooperativeKernel((const void*)k_persist, dim3(256), dim3(512), args, 0, stream);
}